// Round 8
// baseline (143.256 us; speedup 1.0000x reference)
//
#include <hip/hip_runtime.h>
#include <hip/hip_bf16.h>
#include <math.h>

// Problem constants
#define BB 4
#define CC 64
#define HH 128
#define WW 128
#define HW 16384
#define CHW (CC*HW)

typedef __bf16 bf16;
typedef __attribute__((ext_vector_type(8))) __bf16 bf16x8;
typedef __attribute__((ext_vector_type(4))) __bf16 bf16x4;
typedef __attribute__((ext_vector_type(4))) float f32x4;
typedef __attribute__((ext_vector_type(4))) unsigned short u16x4;

#define MFMA(a, b, c) __builtin_amdgcn_mfma_f32_16x16x32_bf16((a), (b), (c), 0, 0, 0)

// ---- Pre-kernel: x NCHW -> NHWC bf16 (blocks 0..1023) + weight frags ----
__global__ __launch_bounds__(256) void k_pre(const float* __restrict__ x,
        bf16* __restrict__ xt,
        const float* __restrict__ dw, const float* __restrict__ ow,
        const float* __restrict__ mw,
        bf16* __restrict__ wfd_hi,
        bf16* __restrict__ wfo_hi, bf16* __restrict__ wfo_lo) {
    __shared__ float tile[64][65];
    if (blockIdx.x < 1024) {
        int b  = blockIdx.x >> 8;
        int s0 = (blockIdx.x & 255) * 64;
        int t  = threadIdx.x;
        const float* xb = x + (size_t)b * CHW;
        int sl = (t & 15) * 4;
        int c0 = t >> 4;
        #pragma unroll
        for (int r = 0; r < 4; ++r) {
            int c = c0 + r * 16;
            float4 v = *(const float4*)&xb[(size_t)c * HW + s0 + sl];
            tile[c][sl]     = v.x;
            tile[c][sl + 1] = v.y;
            tile[c][sl + 2] = v.z;
            tile[c][sl + 3] = v.w;
        }
        __syncthreads();
        int lane = t & 63, w = t >> 6;
        int si = w * 16 + (lane >> 2);
        int cg = (lane & 3) * 16;
        bf16x8 h0, h1;
        #pragma unroll
        for (int j = 0; j < 8; ++j) {
            h0[j] = (bf16)tile[cg + j][si];
            h1[j] = (bf16)tile[cg + 8 + j][si];
        }
        bf16* dst = xt + (size_t)b * CHW + (size_t)(s0 + si) * 64 + cg;
        *(bf16x8*)dst       = h0;
        *(bf16x8*)(dst + 8) = h1;
    } else {
        int idx = (blockIdx.x - 1024) * 256 + threadIdx.x;
        if (idx < 36864) {                          // deform frags (hi only)
            int j    = idx & 7;
            int lane = (idx >> 3) & 63;
            int ks   = (idx >> 9) % 18;
            int nt   = idx / (512 * 18);
            int n    = nt * 16 + (lane & 15);
            int kglob = ks * 32 + (lane >> 4) * 8 + j;
            int kk = kglob >> 6, c = kglob & 63;    // K-order: k = kk*64 + c
            wfd_hi[idx] = (bf16)dw[(n * 64 + c) * 9 + kk];
        } else {
            int idx2 = idx - 36864;                 // offmask frags: hi + lo
            int j    = idx2 & 7;
            int lane = (idx2 >> 3) & 63;
            int ks   = (idx2 >> 9) % 18;
            int nt   = idx2 / (512 * 18);
            int ch   = nt * 16 + (lane & 15);
            int kglob = ks * 32 + (lane >> 4) * 8 + j;
            int kk = kglob >> 6, c = kglob & 63;
            float w = 0.0f;
            if (ch < 18)      w = ow[(ch * 64 + c) * 9 + kk];
            else if (ch < 27) w = mw[((ch - 18) * 64 + c) * 9 + kk];
            bf16 h = (bf16)w;
            wfo_hi[idx2] = h;
            wfo_lo[idx2] = (bf16)(w - (float)h);
        }
    }
}

// ---- Kernel A: offset/mask conv (MFMA) + bilinear scalar precompute ----
__global__ __launch_bounds__(256) void k_offmask(const bf16* __restrict__ xt,
        const bf16* __restrict__ wfo_hi, const bf16* __restrict__ wfo_lo,
        const float* __restrict__ ob, const float* __restrict__ mb,
        bf16* __restrict__ sampw_g, unsigned short* __restrict__ sampo_g) {
    __shared__ float om_s[27 * 64];

    int pos0 = blockIdx.x * 64;
    int wo0 = pos0 & 127;
    int ho  = (pos0 >> 7) & 127;
    int b   = pos0 >> 14;
    int t = threadIdx.x, wave = t >> 6, lane = t & 63;
    int m = lane & 15, g = lane >> 4;
    const bf16* xtb = xt + (size_t)b * CHW;

    // ---- Phase B: offset/mask GEMM, wave = st ----
    {
        int st = wave;
        f32x4 acc0 = {0.f, 0.f, 0.f, 0.f};
        f32x4 acc1 = {0.f, 0.f, 0.f, 0.f};
        const bf16x8* bh0 = (const bf16x8*)wfo_hi + lane;
        const bf16x8* bl0 = (const bf16x8*)wfo_lo + lane;
        const bf16x8* bh1 = (const bf16x8*)wfo_hi + 18 * 64 + lane;
        const bf16x8* bl1 = (const bf16x8*)wfo_lo + 18 * 64 + lane;
        #pragma unroll
        for (int kk = 0; kk < 9; ++kk) {
            int y  = ho + kk / 3 - 1;
            int xx = wo0 + st * 16 + m + (kk % 3) - 1;
            bf16x8 ae = {};
            bf16x8 ao = {};
            if ((unsigned)y < 128u && (unsigned)xx < 128u) {
                const bf16* bp = xtb + ((size_t)(y * 128 + xx) << 6);
                ae = *(const bf16x8*)(bp + g * 8);
                ao = *(const bf16x8*)(bp + 32 + g * 8);
            }
            int ks0 = 2 * kk, ks1 = 2 * kk + 1;
            acc0 = MFMA(ae, bh0[ks0 * 64], acc0);
            acc0 = MFMA(ae, bl0[ks0 * 64], acc0);
            acc0 = MFMA(ao, bh0[ks1 * 64], acc0);
            acc0 = MFMA(ao, bl0[ks1 * 64], acc0);
            acc1 = MFMA(ae, bh1[ks0 * 64], acc1);
            acc1 = MFMA(ae, bl1[ks0 * 64], acc1);
            acc1 = MFMA(ao, bh1[ks1 * 64], acc1);
            acc1 = MFMA(ao, bl1[ks1 * 64], acc1);
        }
        int p64 = st * 16 + g * 4;
        float bias0 = ob[m];
        #pragma unroll
        for (int r = 0; r < 4; ++r)
            om_s[m * 64 + p64 + r] = acc0[r] + bias0;
        int ch1 = 16 + m;
        if (ch1 < 27) {
            float bias1 = (ch1 < 18) ? ob[ch1] : mb[ch1 - 18];
            #pragma unroll
            for (int r = 0; r < 4; ++r) {
                float v = acc1[r] + bias1;
                if (ch1 >= 18) v = 1.0f / (1.0f + __expf(-v));
                om_s[ch1 * 64 + p64 + r] = v;
            }
        }
    }
    __syncthreads();

    // ---- Phase C1: bilinear scalars -> global ----
    for (int tl = t; tl < 576; tl += 256) {
        int p64 = tl / 9, k = tl - p64 * 9;
        float dy = om_s[(2 * k) * 64 + p64];
        float dx = om_s[(2 * k + 1) * 64 + p64];
        float mk = om_s[(18 + k) * 64 + p64];
        float py = (float)(ho - 1 + k / 3) + dy;
        float px = (float)(wo0 + p64 - 1 + (k % 3)) + dx;
        float y0f = floorf(py), x0f = floorf(px);
        float fy = py - y0f, fx = px - x0f;
        int y0 = (int)y0f, x0 = (int)x0f;
        int y1 = y0 + 1,  x1 = x0 + 1;
        bool vy0 = (unsigned)y0 < 128u, vy1 = (unsigned)y1 < 128u;
        bool vx0 = (unsigned)x0 < 128u, vx1 = (unsigned)x1 < 128u;
        int y0c = min(max(y0, 0), 127), y1c = min(max(y1, 0), 127);
        int x0c = min(max(x0, 0), 127), x1c = min(max(x1, 0), 127);
        bf16x4 wv;
        wv.x = (bf16)((vy0 && vx0) ? mk * (1.f - fy) * (1.f - fx) : 0.f);
        wv.y = (bf16)((vy0 && vx1) ? mk * (1.f - fy) * fx         : 0.f);
        wv.z = (bf16)((vy1 && vx0) ? mk * fy * (1.f - fx)         : 0.f);
        wv.w = (bf16)((vy1 && vx1) ? mk * fy * fx                 : 0.f);
        u16x4 ov;
        ov.x = (unsigned short)(y0c * 128 + x0c);
        ov.y = (unsigned short)(y0c * 128 + x1c);
        ov.z = (unsigned short)(y1c * 128 + x0c);
        ov.w = (unsigned short)(y1c * 128 + x1c);
        int gtask = pos0 * 9 + tl;
        *(bf16x4*)&sampw_g[gtask * 4] = wv;
        *(u16x4*)&sampo_g[gtask * 4] = ov;
    }
}

// ---- Kernel B: deform GEMM, barrier-free, wave-private 3-slot LDS pipeline ----
// Each wave owns 16 positions. kk fully unrolled; staging rotates over 3
// wave-private buffers so the compiler can hoist stage k+1/k+2 global loads
// above stage-k MFMAs. No __syncthreads anywhere.
__global__ __launch_bounds__(256, 4) void k_deform(const bf16* __restrict__ xt,
        const bf16* __restrict__ wfd_hi,
        const bf16* __restrict__ sampw_g, const unsigned short* __restrict__ sampo_g,
        const float* __restrict__ db, float* __restrict__ out) {
    __shared__ __align__(16) char stage[4 * 3 * 16 * 144];  // 27648 B

    int t = threadIdx.x, wave = t >> 6, lane = t & 63;
    int m = lane & 15, g = lane >> 6 ? 0 : (lane >> 4);     // g = lane>>4 (0..3)
    g = lane >> 4;
    int p16  = blockIdx.x * 4 + wave;
    int pos0 = p16 * 16;
    int wo0 = pos0 & 127;
    int ho  = (pos0 >> 7) & 127;
    int b   = pos0 >> 14;
    const bf16* xtb = xt + (size_t)b * CHW;
    char* mybuf = stage + wave * (3 * 16 * 144);

    f32x4 acc[4];
    #pragma unroll
    for (int nt = 0; nt < 4; ++nt) acc[nt] = (f32x4){0.f, 0.f, 0.f, 0.f};
    const bf16x8* bhd = (const bf16x8*)wfd_hi + lane;
    int cq8 = m * 8;                                // byte offset of lane's 4-ch slice

    #pragma unroll
    for (int kk = 0; kk < 9; ++kk) {
        char* buf = mybuf + (kk % 3) * (16 * 144);
        #pragma unroll
        for (int it = 0; it < 4; ++it) {
            int s = it * 4 + g;
            int gtask = (pos0 + s) * 9 + kk;
            bf16x4 wb = *(const bf16x4*)&sampw_g[gtask * 4];
            u16x4  o4 = *(const u16x4*)&sampo_g[gtask * 4];
            bf16x4 c0 = *(const bf16x4*)(xtb + ((int)o4.x << 6) + m * 4);
            bf16x4 c1 = *(const bf16x4*)(xtb + ((int)o4.y << 6) + m * 4);
            bf16x4 c2 = *(const bf16x4*)(xtb + ((int)o4.z << 6) + m * 4);
            bf16x4 c3 = *(const bf16x4*)(xtb + ((int)o4.w << 6) + m * 4);
            float w00 = (float)wb.x, w01 = (float)wb.y;
            float w10 = (float)wb.z, w11 = (float)wb.w;
            float r0 = w00 * (float)c0.x + w01 * (float)c1.x + w10 * (float)c2.x + w11 * (float)c3.x;
            float r1 = w00 * (float)c0.y + w01 * (float)c1.y + w10 * (float)c2.y + w11 * (float)c3.y;
            float r2 = w00 * (float)c0.z + w01 * (float)c1.z + w10 * (float)c2.z + w11 * (float)c3.z;
            float r3 = w00 * (float)c0.w + w01 * (float)c1.w + w10 * (float)c2.w + w11 * (float)c3.w;
            bf16x4 hv = {(bf16)r0, (bf16)r1, (bf16)r2, (bf16)r3};
            *(bf16x4*)(buf + s * 144 + cq8) = hv;
        }
        // A-fragments (in-wave lgkmcnt ordering guarantees writes landed)
        bf16x8 a0 = *(const bf16x8*)(buf + m * 144 + g * 16);
        bf16x8 a1 = *(const bf16x8*)(buf + m * 144 + 64 + g * 16);
        int ks0 = 2 * kk, ks1 = ks0 + 1;
        #pragma unroll
        for (int nt = 0; nt < 4; ++nt) {
            acc[nt] = MFMA(a0, bhd[(nt * 18 + ks0) * 64], acc[nt]);
            acc[nt] = MFMA(a1, bhd[(nt * 18 + ks1) * 64], acc[nt]);
        }
    }

    #pragma unroll
    for (int nt = 0; nt < 4; ++nt) {
        int o = nt * 16 + m;
        float bias = db[o];
        float4 vv = {acc[nt][0] + bias, acc[nt][1] + bias,
                     acc[nt][2] + bias, acc[nt][3] + bias};
        *(float4*)&out[((size_t)(b * 64 + o)) * HW + ho * 128 + wo0 + g * 4] = vv;
    }
}

extern "C" void kernel_launch(void* const* d_in, const int* in_sizes, int n_in,
                              void* d_out, int out_size, void* d_ws, size_t ws_size,
                              hipStream_t stream) {
    const float* x   = (const float*)d_in[0];
    const float* ow  = (const float*)d_in[1];
    const float* ob  = (const float*)d_in[2];
    const float* mw  = (const float*)d_in[3];
    const float* mb  = (const float*)d_in[4];
    const float* dw  = (const float*)d_in[5];
    const float* db  = (const float*)d_in[6];
    float* out = (float*)d_out;

    bf16* xt      = (bf16*)d_ws;                    // 4,194,304 bf16 = 8 MB
    bf16* wfd_hi  = xt + (size_t)BB * HW * CC;      // 36864
    bf16* wfo_hi  = wfd_hi + 36864;                 // 18432
    bf16* wfo_lo  = wfo_hi + 18432;                 // 18432
    bf16* sampw_g = wfo_lo + 18432;                 // 589824*4 bf16
    unsigned short* sampo_g = (unsigned short*)(sampw_g + (size_t)589824 * 4);

    k_pre<<<1024 + 216, 256, 0, stream>>>(x, xt, dw, ow, mw, wfd_hi, wfo_hi, wfo_lo);
    k_offmask<<<(BB * HW) / 64, 256, 0, stream>>>(xt, wfo_hi, wfo_lo, ob, mb, sampw_g, sampo_g);
    k_deform<<<(BB * HW) / 64, 256, 0, stream>>>(xt, wfd_hi, sampw_g, sampo_g, db, out);
}

// Round 9
// 135.665 us; speedup vs baseline: 1.0560x; 1.0560x over previous
//
#include <hip/hip_runtime.h>
#include <hip/hip_bf16.h>
#include <math.h>

// Problem constants
#define BB 4
#define CC 64
#define HH 128
#define WW 128
#define HW 16384
#define CHW (CC*HW)

typedef __bf16 bf16;
typedef __attribute__((ext_vector_type(8))) __bf16 bf16x8;
typedef __attribute__((ext_vector_type(4))) __bf16 bf16x4;
typedef __attribute__((ext_vector_type(4))) float f32x4;
typedef __attribute__((ext_vector_type(4))) unsigned short u16x4;

#define MFMA(a, b, c) __builtin_amdgcn_mfma_f32_16x16x32_bf16((a), (b), (c), 0, 0, 0)

// fused bilinear-sample record: 8B weights (bf16x4) + 8B offsets (u16x4)
union PRec {
    float4 f;
    struct { bf16x4 wb; unsigned short o[4]; } s;
};

// ---- Pre-kernel: x NCHW -> NHWC bf16 (blocks 0..1023) + weight frags ----
__global__ __launch_bounds__(256) void k_pre(const float* __restrict__ x,
        bf16* __restrict__ xt,
        const float* __restrict__ dw, const float* __restrict__ ow,
        const float* __restrict__ mw,
        bf16* __restrict__ wfd_hi,
        bf16* __restrict__ wfo_hi, bf16* __restrict__ wfo_lo) {
    __shared__ float tile[64][65];
    if (blockIdx.x < 1024) {
        int b  = blockIdx.x >> 8;
        int s0 = (blockIdx.x & 255) * 64;
        int t  = threadIdx.x;
        const float* xb = x + (size_t)b * CHW;
        int sl = (t & 15) * 4;
        int c0 = t >> 4;
        #pragma unroll
        for (int r = 0; r < 4; ++r) {
            int c = c0 + r * 16;
            float4 v = *(const float4*)&xb[(size_t)c * HW + s0 + sl];
            tile[c][sl]     = v.x;
            tile[c][sl + 1] = v.y;
            tile[c][sl + 2] = v.z;
            tile[c][sl + 3] = v.w;
        }
        __syncthreads();
        int lane = t & 63, w = t >> 6;
        int si = w * 16 + (lane >> 2);
        int cg = (lane & 3) * 16;
        bf16x8 h0, h1;
        #pragma unroll
        for (int j = 0; j < 8; ++j) {
            h0[j] = (bf16)tile[cg + j][si];
            h1[j] = (bf16)tile[cg + 8 + j][si];
        }
        bf16* dst = xt + (size_t)b * CHW + (size_t)(s0 + si) * 64 + cg;
        *(bf16x8*)dst       = h0;
        *(bf16x8*)(dst + 8) = h1;
    } else {
        int idx = (blockIdx.x - 1024) * 256 + threadIdx.x;
        if (idx < 36864) {                          // deform frags (hi only)
            int j    = idx & 7;
            int lane = (idx >> 3) & 63;
            int ks   = (idx >> 9) % 18;
            int nt   = idx / (512 * 18);
            int n    = nt * 16 + (lane & 15);
            int kglob = ks * 32 + (lane >> 4) * 8 + j;
            int kk = kglob >> 6, c = kglob & 63;    // K-order: k = kk*64 + c
            wfd_hi[idx] = (bf16)dw[(n * 64 + c) * 9 + kk];
        } else {
            int idx2 = idx - 36864;                 // offmask frags: hi + lo
            int j    = idx2 & 7;
            int lane = (idx2 >> 3) & 63;
            int ks   = (idx2 >> 9) % 18;
            int nt   = idx2 / (512 * 18);
            int ch   = nt * 16 + (lane & 15);
            int kglob = ks * 32 + (lane >> 4) * 8 + j;
            int kk = kglob >> 6, c = kglob & 63;
            float w = 0.0f;
            if (ch < 18)      w = ow[(ch * 64 + c) * 9 + kk];
            else if (ch < 27) w = mw[((ch - 18) * 64 + c) * 9 + kk];
            bf16 h = (bf16)w;
            wfo_hi[idx2] = h;
            wfo_lo[idx2] = (bf16)(w - (float)h);
        }
    }
}

// ---- Kernel A: offset/mask conv (MFMA) + bilinear scalar precompute ----
__global__ __launch_bounds__(256) void k_offmask(const bf16* __restrict__ xt,
        const bf16* __restrict__ wfo_hi, const bf16* __restrict__ wfo_lo,
        const float* __restrict__ ob, const float* __restrict__ mb,
        float4* __restrict__ samp_g) {
    __shared__ float om_s[27 * 64];

    int pos0 = blockIdx.x * 64;
    int wo0 = pos0 & 127;
    int ho  = (pos0 >> 7) & 127;
    int b   = pos0 >> 14;
    int t = threadIdx.x, wave = t >> 6, lane = t & 63;
    int m = lane & 15, g = lane >> 4;
    const bf16* xtb = xt + (size_t)b * CHW;

    // ---- Phase B: offset/mask GEMM, wave = st ----
    {
        int st = wave;
        f32x4 acc0 = {0.f, 0.f, 0.f, 0.f};
        f32x4 acc1 = {0.f, 0.f, 0.f, 0.f};
        const bf16x8* bh0 = (const bf16x8*)wfo_hi + lane;
        const bf16x8* bl0 = (const bf16x8*)wfo_lo + lane;
        const bf16x8* bh1 = (const bf16x8*)wfo_hi + 18 * 64 + lane;
        const bf16x8* bl1 = (const bf16x8*)wfo_lo + 18 * 64 + lane;
        #pragma unroll
        for (int kk = 0; kk < 9; ++kk) {
            int y  = ho + kk / 3 - 1;
            int xx = wo0 + st * 16 + m + (kk % 3) - 1;
            bf16x8 ae = {};
            bf16x8 ao = {};
            if ((unsigned)y < 128u && (unsigned)xx < 128u) {
                const bf16* bp = xtb + ((size_t)(y * 128 + xx) << 6);
                ae = *(const bf16x8*)(bp + g * 8);
                ao = *(const bf16x8*)(bp + 32 + g * 8);
            }
            int ks0 = 2 * kk, ks1 = 2 * kk + 1;
            acc0 = MFMA(ae, bh0[ks0 * 64], acc0);
            acc0 = MFMA(ae, bl0[ks0 * 64], acc0);
            acc0 = MFMA(ao, bh0[ks1 * 64], acc0);
            acc0 = MFMA(ao, bl0[ks1 * 64], acc0);
            acc1 = MFMA(ae, bh1[ks0 * 64], acc1);
            acc1 = MFMA(ae, bl1[ks0 * 64], acc1);
            acc1 = MFMA(ao, bh1[ks1 * 64], acc1);
            acc1 = MFMA(ao, bl1[ks1 * 64], acc1);
        }
        int p64 = st * 16 + g * 4;
        float bias0 = ob[m];
        #pragma unroll
        for (int r = 0; r < 4; ++r)
            om_s[m * 64 + p64 + r] = acc0[r] + bias0;
        int ch1 = 16 + m;
        if (ch1 < 27) {
            float bias1 = (ch1 < 18) ? ob[ch1] : mb[ch1 - 18];
            #pragma unroll
            for (int r = 0; r < 4; ++r) {
                float v = acc1[r] + bias1;
                if (ch1 >= 18) v = 1.0f / (1.0f + __expf(-v));
                om_s[ch1 * 64 + p64 + r] = v;
            }
        }
    }
    __syncthreads();

    // ---- Phase C1: bilinear scalars -> global (fused 16B records) ----
    for (int tl = t; tl < 576; tl += 256) {
        int p64 = tl / 9, k = tl - p64 * 9;
        float dy = om_s[(2 * k) * 64 + p64];
        float dx = om_s[(2 * k + 1) * 64 + p64];
        float mk = om_s[(18 + k) * 64 + p64];
        float py = (float)(ho - 1 + k / 3) + dy;
        float px = (float)(wo0 + p64 - 1 + (k % 3)) + dx;
        float y0f = floorf(py), x0f = floorf(px);
        float fy = py - y0f, fx = px - x0f;
        int y0 = (int)y0f, x0 = (int)x0f;
        int y1 = y0 + 1,  x1 = x0 + 1;
        bool vy0 = (unsigned)y0 < 128u, vy1 = (unsigned)y1 < 128u;
        bool vx0 = (unsigned)x0 < 128u, vx1 = (unsigned)x1 < 128u;
        int y0c = min(max(y0, 0), 127), y1c = min(max(y1, 0), 127);
        int x0c = min(max(x0, 0), 127), x1c = min(max(x1, 0), 127);
        PRec r;
        r.s.wb.x = (bf16)((vy0 && vx0) ? mk * (1.f - fy) * (1.f - fx) : 0.f);
        r.s.wb.y = (bf16)((vy0 && vx1) ? mk * (1.f - fy) * fx         : 0.f);
        r.s.wb.z = (bf16)((vy1 && vx0) ? mk * fy * (1.f - fx)         : 0.f);
        r.s.wb.w = (bf16)((vy1 && vx1) ? mk * fy * fx                 : 0.f);
        r.s.o[0] = (unsigned short)(y0c * 128 + x0c);
        r.s.o[1] = (unsigned short)(y0c * 128 + x1c);
        r.s.o[2] = (unsigned short)(y1c * 128 + x0c);
        r.s.o[3] = (unsigned short)(y1c * 128 + x1c);
        samp_g[pos0 * 9 + tl] = r.f;
    }
}

// ---- Kernel B: deform GEMM, 1-wave blocks, explicit 2-level SW pipeline ----
// Per stage kk: (1) issue corner loads for kk+1 (params arrived a stage ago),
// (2) combine stage-kk corners -> wave-private LDS, (3) issue params for kk+2,
// (4) ds_read A-frags + 8 MFMA. Register double-buffered; no barriers.
__global__ __launch_bounds__(64, 3) void k_deform(const bf16* __restrict__ xt,
        const bf16* __restrict__ wfd_hi,
        const float4* __restrict__ samp_g,
        const float* __restrict__ db, float* __restrict__ out) {
    __shared__ __align__(16) char stage[2 * 16 * 144];  // 4608 B, wave-private

    int lane = threadIdx.x;
    int m = lane & 15, g = lane >> 4;
    int pos0 = blockIdx.x * 16;
    int wo0 = pos0 & 127;
    int ho  = (pos0 >> 7) & 127;
    int b   = pos0 >> 14;
    const bf16* xtb = xt + (size_t)b * CHW;
    const float4* sp = samp_g + (size_t)pos0 * 9;
    int cq = m * 4;                                 // lane's 4-channel slice

    f32x4 acc[4];
    #pragma unroll
    for (int nt = 0; nt < 4; ++nt) acc[nt] = (f32x4){0.f, 0.f, 0.f, 0.f};
    const bf16x8* bhd = (const bf16x8*)wfd_hi + lane;

    PRec pp0[4], pp1[4];
    bf16x4 cr0[4][4], cr1[4][4];

    // prologue: params kk=0, corners kk=0, params kk=1
    #pragma unroll
    for (int it = 0; it < 4; ++it) pp0[it].f = sp[(it * 4 + g) * 9 + 0];
    #pragma unroll
    for (int it = 0; it < 4; ++it) {
        #pragma unroll
        for (int c = 0; c < 4; ++c)
            cr0[it][c] = *(const bf16x4*)(xtb + ((int)pp0[it].s.o[c] << 6) + cq);
    }
    #pragma unroll
    for (int it = 0; it < 4; ++it) pp1[it].f = sp[(it * 4 + g) * 9 + 1];

    auto stageFn = [&](int kk, PRec (&PPc)[4], bf16x4 (&CRc)[4][4],
                       PRec (&PPn)[4], bf16x4 (&CRn)[4][4]) {
        char* buf = stage + (kk & 1) * 2304;
        // (1) corner loads for stage kk+1
        if (kk + 1 < 9) {
            #pragma unroll
            for (int it = 0; it < 4; ++it) {
                #pragma unroll
                for (int c = 0; c < 4; ++c)
                    CRn[it][c] = *(const bf16x4*)(xtb + ((int)PPn[it].s.o[c] << 6) + cq);
            }
        }
        // (2) combine + stage to LDS
        #pragma unroll
        for (int it = 0; it < 4; ++it) {
            bf16x4 wb = PPc[it].s.wb;
            float w00 = (float)wb.x, w01 = (float)wb.y;
            float w10 = (float)wb.z, w11 = (float)wb.w;
            bf16x4 c0 = CRc[it][0], c1 = CRc[it][1], c2 = CRc[it][2], c3 = CRc[it][3];
            float r0 = w00 * (float)c0.x + w01 * (float)c1.x + w10 * (float)c2.x + w11 * (float)c3.x;
            float r1 = w00 * (float)c0.y + w01 * (float)c1.y + w10 * (float)c2.y + w11 * (float)c3.y;
            float r2 = w00 * (float)c0.z + w01 * (float)c1.z + w10 * (float)c2.z + w11 * (float)c3.z;
            float r3 = w00 * (float)c0.w + w01 * (float)c1.w + w10 * (float)c2.w + w11 * (float)c3.w;
            bf16x4 hv = {(bf16)r0, (bf16)r1, (bf16)r2, (bf16)r3};
            *(bf16x4*)(buf + (it * 4 + g) * 144 + m * 8) = hv;
        }
        // (3) params for stage kk+2 (reuse consumed slot)
        if (kk + 2 < 9) {
            #pragma unroll
            for (int it = 0; it < 4; ++it) PPc[it].f = sp[(it * 4 + g) * 9 + kk + 2];
        }
        // (4) A-frags + MFMA
        bf16x8 a0 = *(const bf16x8*)(buf + m * 144 + g * 16);
        bf16x8 a1 = *(const bf16x8*)(buf + m * 144 + 64 + g * 16);
        int ks0 = 2 * kk, ks1 = ks0 + 1;
        #pragma unroll
        for (int nt = 0; nt < 4; ++nt) {
            acc[nt] = MFMA(a0, bhd[(nt * 18 + ks0) * 64], acc[nt]);
            acc[nt] = MFMA(a1, bhd[(nt * 18 + ks1) * 64], acc[nt]);
        }
    };

    #pragma unroll
    for (int kk = 0; kk < 9; ++kk) {
        if (kk & 1) stageFn(kk, pp1, cr1, pp0, cr0);
        else        stageFn(kk, pp0, cr0, pp1, cr1);
    }

    #pragma unroll
    for (int nt = 0; nt < 4; ++nt) {
        int o = nt * 16 + m;
        float bias = db[o];
        float4 vv = {acc[nt][0] + bias, acc[nt][1] + bias,
                     acc[nt][2] + bias, acc[nt][3] + bias};
        *(float4*)&out[((size_t)(b * 64 + o)) * HW + ho * 128 + wo0 + g * 4] = vv;
    }
}

extern "C" void kernel_launch(void* const* d_in, const int* in_sizes, int n_in,
                              void* d_out, int out_size, void* d_ws, size_t ws_size,
                              hipStream_t stream) {
    const float* x   = (const float*)d_in[0];
    const float* ow  = (const float*)d_in[1];
    const float* ob  = (const float*)d_in[2];
    const float* mw  = (const float*)d_in[3];
    const float* mb  = (const float*)d_in[4];
    const float* dw  = (const float*)d_in[5];
    const float* db  = (const float*)d_in[6];
    float* out = (float*)d_out;

    bf16* xt      = (bf16*)d_ws;                    // 4,194,304 bf16 = 8 MB
    bf16* wfd_hi  = xt + (size_t)BB * HW * CC;      // 36864
    bf16* wfo_hi  = wfd_hi + 36864;                 // 18432
    bf16* wfo_lo  = wfo_hi + 18432;                 // 18432
    float4* samp_g = (float4*)(wfo_lo + 18432 + 8); // 589824 x 16B, 16B-aligned

    k_pre<<<1024 + 216, 256, 0, stream>>>(x, xt, dw, ow, mw, wfd_hi, wfo_hi, wfo_lo);
    k_offmask<<<(BB * HW) / 64, 256, 0, stream>>>(xt, wfo_hi, wfo_lo, ob, mb, samp_g);
    k_deform<<<(BB * HW) / 16, 64, 0, stream>>>(xt, wfd_hi, samp_g, db, out);
}